// Round 5
// baseline (189.382 us; speedup 1.0000x reference)
//
#include <hip/hip_runtime.h>
#include <hip/hip_fp16.h>

// PQ sim: sim = decode(x) @ decode(tgt)^T via f16 GEMM (K=512).
// GEMM: 256x256 tile, BK=64, 8 waves (2Mx4N, wave-tile 128x64), 8-phase
// schedule (T3+T4 counted vmcnt(2)), st_16x32 LDS swizzle via pre-swizzled
// global source (T2, rule #21), setprio (T5), per-XCD bn-stripe mapping (T1+)
// and non-temporal C stores to keep A'/B' L2/L3-resident.

#define D_FULL 512
#define M_SUB 64
#define KSUB 256
#define DSUB 8
#define KP 512

typedef _Float16 f16x8 __attribute__((ext_vector_type(8)));
typedef float f32x4 __attribute__((ext_vector_type(4)));

static __device__ __forceinline__ unsigned int pack2h(float f0, float f1) {
  _Float16 h0 = (_Float16)f0, h1 = (_Float16)f1;
  unsigned short u0, u1;
  __builtin_memcpy(&u0, &h0, 2);
  __builtin_memcpy(&u1, &h1, 2);
  return (unsigned int)u0 | ((unsigned int)u1 << 16);
}

// ---------------- encode + decode queries into A' (f16) ----------------
__global__ void encode_kernel(const float* __restrict__ x,
                              const float* __restrict__ cen,
                              unsigned short* __restrict__ Ap) {
  __shared__ float cs[KSUB][DSUB];
  __shared__ float n2[KSUB];
  const int t = threadIdx.x;
  const int s = blockIdx.x;
  const int i = blockIdx.y * 256 + t;

  const float* cp = cen + ((size_t)s * KSUB + t) * DSUB;
  float4 c0 = *(const float4*)cp;
  float4 c1 = *(const float4*)(cp + 4);
  *(float4*)&cs[t][0] = c0;
  *(float4*)&cs[t][4] = c1;
  n2[t] = c0.x * c0.x + c0.y * c0.y + c0.z * c0.z + c0.w * c0.w +
          c1.x * c1.x + c1.y * c1.y + c1.z * c1.z + c1.w * c1.w;
  __syncthreads();

  float xq[8];
  const float* xp = x + (size_t)i * D_FULL + s * DSUB;
  *(float4*)&xq[0] = *(const float4*)xp;
  *(float4*)&xq[4] = *(const float4*)(xp + 4);

  float best = 1e30f;
  int bk = 0;
#pragma unroll 4
  for (int k = 0; k < KSUB; ++k) {
    float dot = 0.f;
#pragma unroll
    for (int d = 0; d < 8; ++d) dot += cs[k][d] * xq[d];
    float dis = n2[k] - 2.0f * dot;
    if (dis < best) { best = dis; bk = k; }  // strict < = numpy argmin tie rule
  }

  uint4 hv;
  hv.x = pack2h(cs[bk][0], cs[bk][1]);
  hv.y = pack2h(cs[bk][2], cs[bk][3]);
  hv.z = pack2h(cs[bk][4], cs[bk][5]);
  hv.w = pack2h(cs[bk][6], cs[bk][7]);
  *(uint4*)(Ap + (size_t)i * KP + s * DSUB) = hv;
}

// ---------------- decode targets into B' (f16) ----------------
__global__ void decode_tgt(const int* __restrict__ tgt,
                           const float* __restrict__ cen,
                           unsigned short* __restrict__ Bp) {
  int g = blockIdx.x * 256 + threadIdx.x;
  int j = g >> 6, s = g & 63;
  int k = tgt[g];
  const float* c = cen + ((size_t)s * KSUB + k) * DSUB;
  float4 v0 = *(const float4*)c;
  float4 v1 = *(const float4*)(c + 4);
  uint4 hv;
  hv.x = pack2h(v0.x, v0.y);
  hv.y = pack2h(v0.z, v0.w);
  hv.z = pack2h(v1.x, v1.y);
  hv.w = pack2h(v1.z, v1.w);
  *(uint4*)(Bp + (size_t)j * KP + s * DSUB) = hv;
}

// ---------------- GEMM: C[n,m] = A'[n,KP] * B'[m,KP]^T ----------------
// LDS: 2 dbuf x {A,B} x 2 col-halves(ks) x [256 rows x 32 cols f16] = 128 KB.
// Unit (16KB): 16 subtiles (16r x 32c, 1KB); swizzle flips byte-bit5 (16 f16)
// when r16>=8. Stage = linear dest + inverse-swz source (rule #21).
#define LDSOFF(d, ab, ks) ((d)*32768 + (ab)*16384 + (ks)*8192)

#define S(tile, ab, ks)                                                        \
  {                                                                            \
    const unsigned short* sp =                                                 \
        ((ab) ? Bb : Ab) + (size_t)((tile)*64 + (ks)*32) + srcoff;             \
    unsigned short* dp = lds + LDSOFF((tile)&1, ab, ks) + dst8;                \
    __builtin_amdgcn_global_load_lds(                                          \
        (const __attribute__((address_space(1))) void*)sp,                     \
        (__attribute__((address_space(3))) void*)dp, 16, 0, 0);                \
    __builtin_amdgcn_global_load_lds(                                          \
        (const __attribute__((address_space(1))) void*)(sp + 128 * KP),        \
        (__attribute__((address_space(3))) void*)(dp + 4096), 16, 0, 0);       \
  }

#define VMW2 asm volatile("s_waitcnt vmcnt(2)" ::: "memory")
#define VMW0 asm volatile("s_waitcnt vmcnt(0)" ::: "memory")
#define BARM asm volatile("s_barrier" ::: "memory")

// Phase: ds-read frags (4A+4B at mq0; 4A at mq1, B reused in regs),
// issue 1 stage unit, barrier, MFMA quadrant (16), [vmcnt], barrier.
#define PH(d, ks, mq, STG, VM)                                                 \
  {                                                                            \
    if ((mq) == 0) {                                                           \
      const unsigned short* bp = lds + LDSOFF(d, 1, ks) + wn * 2048 + vread;   \
      _Pragma("unroll") for (int j = 0; j < 4; ++j)                            \
          b[j] = *(const f16x8*)(bp + j * 512);                                \
    }                                                                          \
    const unsigned short* ap =                                                 \
        lds + LDSOFF(d, 0, ks) + (wm * 8 + (mq)*4) * 512 + vread;              \
    f16x8 a[4];                                                                \
    _Pragma("unroll") for (int i = 0; i < 4; ++i)                              \
        a[i] = *(const f16x8*)(ap + i * 512);                                  \
    STG;                                                                       \
    BARM;                                                                      \
    __builtin_amdgcn_s_setprio(1);                                             \
    _Pragma("unroll") for (int i = 0; i < 4; ++i)                              \
        _Pragma("unroll") for (int j = 0; j < 4; ++j)                          \
            acc[(mq)*4 + i][j] = __builtin_amdgcn_mfma_f32_16x16x32_f16(       \
                a[i], b[j], acc[(mq)*4 + i][j], 0, 0, 0);                      \
    __builtin_amdgcn_s_setprio(0);                                             \
    VM;                                                                        \
    BARM;                                                                      \
  }

// One iteration = 2 K-tiles (e in dbuf0, o in dbuf1), 8 phases.
// Stage stream: (1):oA1 (2):oB1 (3):n2A0 (4):n2B0+vm2 (5):n2A1 (6):n2B1
// (7):n3A0 (8):n3B0+vm2. vmcnt(2) leaves only the 2 units issued in the
// 2 phases right before it; every unit lands >=1 drain before first read.
#define ITER(e, o, n2, n3)                                                     \
  PH(0, 0, 0, S(o, 0, 1), ) PH(0, 0, 1, S(o, 1, 1), )                          \
  PH(0, 1, 0, S(n2, 0, 0), ) PH(0, 1, 1, S(n2, 1, 0), VMW2)                    \
  PH(1, 0, 0, S(n2, 0, 1), ) PH(1, 0, 1, S(n2, 1, 1), )                        \
  PH(1, 1, 0, S(n3, 0, 0), ) PH(1, 1, 1, S(n3, 1, 0), VMW2)

__global__ __launch_bounds__(512, 2) void gemm_nt(
    const unsigned short* __restrict__ A, const unsigned short* __restrict__ B,
    float* __restrict__ C, int Nt) {
  __shared__ unsigned short lds[65536];  // 128 KB
  const int tid = threadIdx.x;
  const int w = tid >> 6, l = tid & 63;
  const int wm = w >> 2, wn = w & 3;

  // Read-side swizzled per-thread LDS offset (f16 units within a unit).
  const int vread = (((l & 15) * 32 + (l >> 4) * 8)) ^ ((l & 8) ? 16 : 0);
  // Stage-side: linear dest tid*8; inverse-swizzled global source offset.
  const int r16s = (tid >> 2) & 15;
  const size_t srcoff =
      (size_t)((tid >> 6) * 16 + r16s) * KP +
      (((tid & 3) * 8) ^ ((r16s & 8) ? 16 : 0));
  const int dst8 = tid * 8;

  // Per-XCD bn-stripe: XCD x owns bn in [x*8, x*8+8) -> its 8 B-panels (2 MB)
  // stay L2-resident all kernel. Within XCD, walk bm in 8-panel supertiles
  // (concurrent ~32 blocks span 8bm x 4bn: A 2 MB + B 1 MB, both L2-fit).
  const int bid = blockIdx.x;
  const int xcd = bid & 7;
  const int idx = bid >> 3;                        // 0..127 per XCD
  const int bm = ((idx >> 6) << 3) | (idx & 7);    // 0..15
  const int bn = xcd * 8 + ((idx >> 3) & 7);       // 0..63

  const unsigned short* Ab = A + (size_t)bm * 256 * KP;
  const unsigned short* Bb = B + (size_t)bn * 256 * KP;

  f32x4 acc[8][4] = {};
  f16x8 b[4];

  // Prologue: T0 all 4 units + T1 ks0; drain to 2 -> T0 fully landed.
  S(0, 0, 0) S(0, 1, 0) S(0, 0, 1) S(0, 1, 1) S(1, 0, 0) S(1, 1, 0)
  VMW2;
  BARM;

  ITER(0, 1, 2, 3)
  ITER(2, 3, 4, 5)
  ITER(4, 5, 6, 7)
  // Tail iter (tiles 6,7): stage only T7 ks1; full drain at phase 4.
  PH(0, 0, 0, S(7, 0, 1), ) PH(0, 0, 1, S(7, 1, 1), )
  PH(0, 1, 0, , ) PH(0, 1, 1, , VMW0)
  PH(1, 0, 0, , ) PH(1, 0, 1, , )
  PH(1, 1, 0, , ) PH(1, 1, 1, , )

  // Epilogue: C/D layout col=lane&15, row=(lane>>4)*4+reg (m89/m91).
  // Non-temporal: don't let the 268 MB C stream evict A'/B' from L2/L3.
  const int rb = bm * 256 + wm * 128 + (l >> 4) * 4;
  const int cb = bn * 256 + wn * 64 + (l & 15);
#pragma unroll
  for (int mi = 0; mi < 8; ++mi)
#pragma unroll
    for (int nj = 0; nj < 4; ++nj)
#pragma unroll
      for (int r = 0; r < 4; ++r)
        __builtin_nontemporal_store(
            acc[mi][nj][r],
            &C[(size_t)(rb + mi * 16 + r) * Nt + cb + nj * 16]);
}

extern "C" void kernel_launch(void* const* d_in, const int* in_sizes, int n_in,
                              void* d_out, int out_size, void* d_ws, size_t ws_size,
                              hipStream_t stream) {
  const float* x = (const float*)d_in[0];    // [n, 512]
  const float* cen = (const float*)d_in[1];  // [64, 256, 8]
  const int* tgt = (const int*)d_in[2];      // [m, 64]
  float* out = (float*)d_out;                // [n, m]
  const int n = in_sizes[0] / D_FULL;        // 4096
  const int m = in_sizes[2] / M_SUB;         // 16384

  unsigned short* Ap = (unsigned short*)d_ws;  // [n, 512] f16
  unsigned short* Bp = Ap + (size_t)n * KP;    // [m, 512] f16

  encode_kernel<<<dim3(M_SUB, n / 256), 256, 0, stream>>>(x, cen, Ap);
  decode_tgt<<<dim3((m * M_SUB) / 256), 256, 0, stream>>>(tgt, cen, Bp);
  gemm_nt<<<dim3((n / 256) * (m / 256)), 512, 0, stream>>>(Ap, Bp, out, m);
}

// Round 6
// 140.406 us; speedup vs baseline: 1.3488x; 1.3488x over previous
//
#include <hip/hip_runtime.h>
#include <hip/hip_fp16.h>

// PQ sim: sim = decode(x) @ decode(tgt)^T via f16 GEMM (K=512).
// GEMM: BM=256 BN=128 BK=64, 8 waves (4Mx2N), ring-of-3 LDS (144 KB),
// counted vmcnt(6) (T4), XOR slot swizzle (T2), setprio (T5).
// R6: XCD-pinned supertile mapping — each XCD owns a 16-panel bn-stripe
// (2 MB, L2-resident); walks 4bm x 16bn supertiles bm-fastest so the 32
// concurrent blocks/XCD share a ~2 MB L2 working set. B' read once per XCD.

#define D_FULL 512
#define M_SUB 64
#define KSUB 256
#define DSUB 8
#define KP 512

typedef _Float16 f16x8 __attribute__((ext_vector_type(8)));
typedef float f32x4 __attribute__((ext_vector_type(4)));

static __device__ __forceinline__ unsigned int pack2h(float f0, float f1) {
  _Float16 h0 = (_Float16)f0, h1 = (_Float16)f1;
  unsigned short u0, u1;
  __builtin_memcpy(&u0, &h0, 2);
  __builtin_memcpy(&u1, &h1, 2);
  return (unsigned int)u0 | ((unsigned int)u1 << 16);
}

// ---------------- encode + decode queries into A' (f16) ----------------
__global__ void encode_kernel(const float* __restrict__ x,
                              const float* __restrict__ cen,
                              unsigned short* __restrict__ Ap) {
  __shared__ float cs[KSUB][DSUB];
  __shared__ float n2[KSUB];
  const int t = threadIdx.x;
  const int s = blockIdx.x;
  const int i = blockIdx.y * 256 + t;

  const float* cp = cen + ((size_t)s * KSUB + t) * DSUB;
  float4 c0 = *(const float4*)cp;
  float4 c1 = *(const float4*)(cp + 4);
  *(float4*)&cs[t][0] = c0;
  *(float4*)&cs[t][4] = c1;
  n2[t] = c0.x * c0.x + c0.y * c0.y + c0.z * c0.z + c0.w * c0.w +
          c1.x * c1.x + c1.y * c1.y + c1.z * c1.z + c1.w * c1.w;
  __syncthreads();

  float xq[8];
  const float* xp = x + (size_t)i * D_FULL + s * DSUB;
  *(float4*)&xq[0] = *(const float4*)xp;
  *(float4*)&xq[4] = *(const float4*)(xp + 4);

  float best = 1e30f;
  int bk = 0;
  for (int k = 0; k < KSUB; ++k) {
    float dot = 0.f;
#pragma unroll
    for (int d = 0; d < 8; ++d) dot += cs[k][d] * xq[d];
    float dis = n2[k] - 2.0f * dot;
    if (dis < best) { best = dis; bk = k; }  // strict < = numpy argmin tie rule
  }

  uint4 hv;
  hv.x = pack2h(cs[bk][0], cs[bk][1]);
  hv.y = pack2h(cs[bk][2], cs[bk][3]);
  hv.z = pack2h(cs[bk][4], cs[bk][5]);
  hv.w = pack2h(cs[bk][6], cs[bk][7]);
  *(uint4*)(Ap + (size_t)i * KP + s * DSUB) = hv;
}

// ---------------- decode targets into B' (f16) ----------------
__global__ void decode_tgt(const int* __restrict__ tgt,
                           const float* __restrict__ cen,
                           unsigned short* __restrict__ Bp) {
  int g = blockIdx.x * 256 + threadIdx.x;
  int j = g >> 6, s = g & 63;
  int k = tgt[g];
  const float* c = cen + ((size_t)s * KSUB + k) * DSUB;
  float4 v0 = *(const float4*)c;
  float4 v1 = *(const float4*)(c + 4);
  uint4 hv;
  hv.x = pack2h(v0.x, v0.y);
  hv.y = pack2h(v0.z, v0.w);
  hv.z = pack2h(v1.x, v1.y);
  hv.w = pack2h(v1.z, v1.w);
  *(uint4*)(Bp + (size_t)j * KP + s * DSUB) = hv;
}

// ---------------- GEMM: C[n,m] = A'[n,KP] * B'[m,KP]^T ----------------
// Stage tile T (BK=64 slice) into LDS slot. Per wave: 4 A-loads + 2 B-loads
// = 6 global_load_lds (vmcnt-tracked). LDS dest is linear (wave base+lane*16);
// swizzle applied on the GLOBAL source (rule #21) + matching read-side XOR.
#define STAGE(T, SLOT)                                                          \
  do {                                                                          \
    const int k0_ = (T) * 64;                                                   \
    unsigned short* as_ = &lds[(SLOT) * 24576];                                 \
    unsigned short* bs_ = as_ + 16384;                                          \
    _Pragma("unroll") for (int it = 0; it < 4; ++it) {                          \
      int R = w * 32 + it * 8;                                                  \
      int r = R + (l >> 3);                                                     \
      int c = (l & 7) ^ (r & 7);                                                \
      __builtin_amdgcn_global_load_lds(                                         \
          (const __attribute__((address_space(1))) void*)(Ab + (size_t)r * KP + \
                                                          k0_ + c * 8),         \
          (__attribute__((address_space(3))) void*)(as_ + R * 64 + l * 8), 16,  \
          0, 0);                                                                \
    }                                                                           \
    _Pragma("unroll") for (int it = 0; it < 2; ++it) {                          \
      int R = w * 16 + it * 8;                                                  \
      int r = R + (l >> 3);                                                     \
      int c = (l & 7) ^ (r & 7);                                                \
      __builtin_amdgcn_global_load_lds(                                         \
          (const __attribute__((address_space(1))) void*)(Bb + (size_t)r * KP + \
                                                          k0_ + c * 8),         \
          (__attribute__((address_space(3))) void*)(bs_ + R * 64 + l * 8), 16,  \
          0, 0);                                                                \
    }                                                                           \
  } while (0)

// Consume one K-tile from SLOT: 16 ds_read_b128 + 32 MFMA per wave.
#define COMPUTE(SLOT)                                                           \
  do {                                                                          \
    const unsigned short* as_ = &lds[(SLOT) * 24576];                           \
    const unsigned short* bs_ = as_ + 16384;                                    \
    _Pragma("unroll") for (int ks = 0; ks < 2; ++ks) {                          \
      f16x8 a_[4], b_[4];                                                       \
      int kq = ks * 4 + (l >> 4);                                               \
      _Pragma("unroll") for (int i2 = 0; i2 < 4; ++i2) {                        \
        int row = wm * 64 + i2 * 16 + (l & 15);                                 \
        a_[i2] = *(const f16x8*)&as_[row * 64 + ((kq ^ (row & 7)) * 8)];        \
      }                                                                         \
      _Pragma("unroll") for (int j2 = 0; j2 < 4; ++j2) {                        \
        int row = wn * 64 + j2 * 16 + (l & 15);                                 \
        b_[j2] = *(const f16x8*)&bs_[row * 64 + ((kq ^ (row & 7)) * 8)];        \
      }                                                                         \
      __builtin_amdgcn_s_setprio(1);                                            \
      _Pragma("unroll") for (int i2 = 0; i2 < 4; ++i2)                          \
          _Pragma("unroll") for (int j2 = 0; j2 < 4; ++j2) acc[i2][j2] =        \
          __builtin_amdgcn_mfma_f32_16x16x32_f16(a_[i2], b_[j2], acc[i2][j2],   \
                                                 0, 0, 0);                      \
      __builtin_amdgcn_s_setprio(0);                                            \
    }                                                                           \
  } while (0)

#define VMW(N) asm volatile("s_waitcnt vmcnt(" #N ")" ::: "memory")
#define BAR() __builtin_amdgcn_s_barrier()

__global__ __launch_bounds__(512, 2) void gemm_nt(
    const unsigned short* __restrict__ A, const unsigned short* __restrict__ B,
    float* __restrict__ C, int Nt) {
  __shared__ unsigned short lds[3 * 24576];  // 3 slots x (A 32KB + B 16KB) = 144 KB
  const int tid = threadIdx.x;
  const int w = tid >> 6, l = tid & 63;
  const int wm = w >> 1, wn = w & 1;

  // R6 mapping: XCD x owns bn-stripe [x*16, x*16+16) (2 MB B, L2-resident).
  // Within XCD: supertile = 4 bm x 16 bn, walked bm-fastest. Concurrent 32
  // blocks/XCD span 4 bm x 8 bn = 1 MB A + 1 MB B in L2.
  const int bid = blockIdx.x;
  const int xcd = bid & 7;
  const int idx = bid >> 3;              // 0..255 per XCD
  const int st = idx >> 6;               // supertile row group 0..3
  const int bm = st * 4 + (idx & 3);     // 0..15
  const int bn = xcd * 16 + ((idx >> 2) & 15);  // 0..127

  const unsigned short* Ab = A + (size_t)bm * 256 * KP;
  const unsigned short* Bb = B + (size_t)bn * 128 * KP;

  f32x4 acc[4][4] = {};

  // Prologue: depth-2 prefetch. Outstanding 12; drain tile0 (oldest 6).
  STAGE(0, 0);
  STAGE(1, 1);
  VMW(6);
  BAR();

  // Steady state: stage t+2 into the slot freed at the previous boundary,
  // compute t, then drain tile t+1's 6 loads (leave t+2's 6 in flight).
  STAGE(2, 2); COMPUTE(0); VMW(6); BAR();  // t=0
  STAGE(3, 0); COMPUTE(1); VMW(6); BAR();  // t=1
  STAGE(4, 1); COMPUTE(2); VMW(6); BAR();  // t=2
  STAGE(5, 2); COMPUTE(0); VMW(6); BAR();  // t=3
  STAGE(6, 0); COMPUTE(1); VMW(6); BAR();  // t=4
  STAGE(7, 1); COMPUTE(2); VMW(6); BAR();  // t=5
  COMPUTE(0); VMW(0); BAR();               // t=6 (tail: drain tile 7)
  COMPUTE(1);                              // t=7

  // Epilogue: C/D layout col=lane&15, row=(lane>>4)*4+reg (verified m89/m91).
  const int rb = bm * 256 + wm * 64 + (l >> 4) * 4;
  const int cb = bn * 128 + wn * 64 + (l & 15);
#pragma unroll
  for (int i2 = 0; i2 < 4; ++i2)
#pragma unroll
    for (int j2 = 0; j2 < 4; ++j2)
#pragma unroll
      for (int r = 0; r < 4; ++r)
        C[(size_t)(rb + i2 * 16 + r) * Nt + cb + j2 * 16] = acc[i2][j2][r];
}

extern "C" void kernel_launch(void* const* d_in, const int* in_sizes, int n_in,
                              void* d_out, int out_size, void* d_ws, size_t ws_size,
                              hipStream_t stream) {
  const float* x = (const float*)d_in[0];    // [n, 512]
  const float* cen = (const float*)d_in[1];  // [64, 256, 8]
  const int* tgt = (const int*)d_in[2];      // [m, 64]
  float* out = (float*)d_out;                // [n, m]
  const int n = in_sizes[0] / D_FULL;        // 4096
  const int m = in_sizes[2] / M_SUB;         // 16384

  unsigned short* Ap = (unsigned short*)d_ws;  // [n, 512] f16
  unsigned short* Bp = Ap + (size_t)n * KP;    // [m, 512] f16

  encode_kernel<<<dim3(M_SUB, n / 256), 256, 0, stream>>>(x, cen, Ap);
  decode_tgt<<<dim3((m * M_SUB) / 256), 256, 0, stream>>>(tgt, cen, Bp);
  gemm_nt<<<dim3((n / 256) * (m / 128)), 512, 0, stream>>>(Ap, Bp, out, m);
}